// Round 8
// baseline (284.647 us; speedup 1.0000x reference)
//
#include <hip/hip_runtime.h>
#include <hip/hip_bf16.h>

// Problem constants
#define S_TOT 37448      // input tokens per sample
#define OUT_ROWS 5704    // output rows per sample
#define EDIM 256
#define BATCH 8

typedef __attribute__((ext_vector_type(8))) short short8;
typedef __attribute__((ext_vector_type(4))) float f32x4;

__device__ __forceinline__ short f2b(float f) {   // f32 -> bf16 RNE
    unsigned u = __builtin_bit_cast(unsigned, f);
    unsigned r = (u + 0x7fffu + ((u >> 16) & 1u)) >> 16;
    return (short)r;
}

// Sum 5 f32x8 table rows; return f32 in s[8]
__device__ __forceinline__ void embed8f(const float* ve, const float* de,
                                        const float* q0, const float* q1, const float* q2,
                                        float* s) {
#pragma unroll
    for (int h = 0; h < 2; ++h) {
        f32x4 a = *(const f32x4*)(ve + h * 4);
        f32x4 b = *(const f32x4*)(de + h * 4);
        f32x4 c = *(const f32x4*)(q0 + h * 4);
        f32x4 d = *(const f32x4*)(q1 + h * 4);
        f32x4 e = *(const f32x4*)(q2 + h * 4);
#pragma unroll
        for (int j = 0; j < 4; ++j)
            s[h * 4 + j] = a[j] + b[j] + c[j] + d[j] + e[j];
    }
}

// -------- weight pre-transform: w[o,i,k] (f32) -> bf16 MFMA B-fragment packed --------
// Wt2[((kb*16 + nf)*64 + l)*8 + j] = bf16(B[kb*32 + (l>>4)*8 + j][nf*16 + (l&15)])
// where B[kappa][o] = w[o, i=kappa%256, kpos=kappa/256]   (kappa = kpos*256 + i)
template <int S>
__global__ __launch_bounds__(256) void transform_kernel(const float* __restrict__ w,
                                                        short* __restrict__ dst) {
    int idx = blockIdx.x * 256 + threadIdx.x;   // [0, K/32 * 16 * 64)
    int l  = idx & 63;
    int nf = (idx >> 6) & 15;
    int kb = idx >> 10;
    int o = nf * 16 + (l & 15);
    int kap0 = kb * 32 + ((l >> 4) << 3);
    short8 r;
#pragma unroll
    for (int j = 0; j < 8; ++j) {
        int kap = kap0 + j;
        int kpos = kap >> 8;
        int i = kap & 255;
        r[j] = f2b(w[(o * 256 + i) * S + kpos]);
    }
    *(short8*)(dst + idx * 8) = r;
}

// -------- layers 0..2: pure embedding, straight to out rows [0, 584), f32 out --------
__global__ __launch_bounds__(256) void embed_small_kernel(
        const int* __restrict__ value, const int* __restrict__ depth,
        const int* __restrict__ position, const float* __restrict__ val_emb,
        const float* __restrict__ dep_emb, const float* __restrict__ pos_emb,
        float* __restrict__ out) {
    int idx = blockIdx.x * 256 + threadIdx.x;
    int token = idx >> 5;            // [0, 8*584)
    int f0 = (idx & 31) * 8;
    int b = token / 584;
    int r = token - b * 584;
    int li = (r < 8) ? 0 : (r < 72 ? 1 : 2);
    int base = b * S_TOT + r;        // input token index == out row for layers 0..2
    int v = value[base];
    int d = depth[base];
    const int* pp = position + base * 3;
    const float* ve = val_emb + ((li * 17 + v) << 8) + f0;
    const float* de = dep_emb + ((li * 33 + d) << 8) + f0;
    const float* q0 = pos_emb + (((li * 3 + 0) * 64 + pp[0]) << 8) + f0;
    const float* q1 = pos_emb + (((li * 3 + 1) * 64 + pp[1]) << 8) + f0;
    const float* q2 = pos_emb + (((li * 3 + 2) * 64 + pp[2]) << 8) + f0;
    float s[8];
    embed8f(ve, de, q0, q1, q2, s);
    float* op = out + ((long)b * OUT_ROWS + r) * EDIM + f0;
    *(f32x4*)op = (f32x4){s[0], s[1], s[2], s[3]};
    *(f32x4*)(op + 4) = (f32x4){s[4], s[5], s[6], s[7]};
}

// -------- fused embed + conv (blockwise GEMM), f32 out --------
// out[m, o] = bias[o] + sum_kappa A[m][kappa] * B[kappa][o]
// A[m][kappa=kpos*256+i] = embed(token (l0+m)*S + kpos + OFF_IN)[i]
// Block: 256 threads = 4 waves (2 M x 2 N), BM=64 rows, N=256 full.
template <int S>
__global__ __launch_bounds__(256) void conv_kernel(
        const int* __restrict__ value, const int* __restrict__ depth,
        const int* __restrict__ position, const float* __restrict__ val_emb,
        const float* __restrict__ dep_emb, const float* __restrict__ pos_emb,
        const short* __restrict__ wt2, const float* __restrict__ bias,
        float* __restrict__ out) {
    constexpr int LI = (S == 4) ? 3 : 4;
    constexpr int L_OUT = (S == 4) ? 1024 : 4096;
    constexpr int OFF_IN = (S == 4) ? 584 : 4680;
    constexpr int OFF_OUT = (S == 4) ? 584 : 1608;

    __shared__ __align__(16) short As[64 * 256];   // 32 KB, one token-slot chunk

    const int tid = threadIdx.x;
    const int lane = tid & 63;
    const int wid = tid >> 6;
    const int wave_m = wid >> 1;
    const int wave_n = wid & 1;
    const int mg0 = blockIdx.x * 64;
    const int b = mg0 / L_OUT;
    const int l0 = mg0 - b * L_OUT;

    f32x4 acc[2][8];
#pragma unroll
    for (int i = 0; i < 2; ++i)
#pragma unroll
        for (int j = 0; j < 8; ++j) acc[i][j] = (f32x4){0.f, 0.f, 0.f, 0.f};

    const int tk = tid >> 5;          // token slot 0..7 in each staging octet
    const int f0 = (tid & 31) * 8;    // feature offset

    for (int cp = 0; cp < S; ++cp) {
        __syncthreads();
        // stage: 64 tokens (the cp-th token of each window), embeddings on the fly
#pragma unroll
        for (int m8 = 0; m8 < 8; ++m8) {
            int m = m8 * 8 + tk;
            int t = OFF_IN + (l0 + m) * S + cp;
            int base = b * S_TOT + t;
            int v = value[base];
            int d = depth[base];
            const int* pp = position + base * 3;
            const float* ve = val_emb + ((LI * 17 + v) << 8) + f0;
            const float* de = dep_emb + ((LI * 33 + d) << 8) + f0;
            const float* q0 = pos_emb + (((LI * 3 + 0) * 64 + pp[0]) << 8) + f0;
            const float* q1 = pos_emb + (((LI * 3 + 1) * 64 + pp[1]) << 8) + f0;
            const float* q2 = pos_emb + (((LI * 3 + 2) * 64 + pp[2]) << 8) + f0;
            float s[8];
            embed8f(ve, de, q0, q1, q2, s);
            short8 r;
#pragma unroll
            for (int j = 0; j < 8; ++j) r[j] = f2b(s[j]);
            int byte = (m * 512 + f0 * 2) ^ ((m & 7) << 4);   // XOR-swizzle vs bank 0 pileup
            *(short8*)((char*)As + byte) = r;
        }
        __syncthreads();
        // 8 MFMA K-steps over this 256-wide kappa chunk
#pragma unroll
        for (int ks = 0; ks < 8; ++ks) {
            short8 af[2];
#pragma unroll
            for (int mf = 0; mf < 2; ++mf) {
                int m = wave_m * 32 + mf * 16 + (lane & 15);
                int byte = (m * 512 + ks * 64 + ((lane >> 4) << 4)) ^ ((m & 7) << 4);
                af[mf] = *(const short8*)((const char*)As + byte);
            }
            int kbg = cp * 8 + ks;
#pragma unroll
            for (int nf = 0; nf < 8; ++nf) {
                int nfg = wave_n * 8 + nf;
                short8 bfr = *(const short8*)(wt2 + ((kbg * 16 + nfg) * 64 + lane) * 8);
                acc[0][nf] = __builtin_amdgcn_mfma_f32_16x16x32_bf16(af[0], bfr, acc[0][nf], 0, 0, 0);
                acc[1][nf] = __builtin_amdgcn_mfma_f32_16x16x32_bf16(af[1], bfr, acc[1][nf], 0, 0, 0);
            }
        }
    }

    // epilogue: C frag layout col=lane&15, row=(lane>>4)*4+reg  [m89-verified]
#pragma unroll
    for (int mf = 0; mf < 2; ++mf) {
#pragma unroll
        for (int nf = 0; nf < 8; ++nf) {
            int n = wave_n * 128 + nf * 16 + (lane & 15);
            float bv = bias[n];
            int r0 = l0 + wave_m * 32 + mf * 16 + ((lane >> 4) << 2);
#pragma unroll
            for (int reg = 0; reg < 4; ++reg) {
                out[((long)b * OUT_ROWS + OFF_OUT + r0 + reg) * EDIM + n] =
                    acc[mf][nf][reg] + bv;
            }
        }
    }
}

extern "C" void kernel_launch(void* const* d_in, const int* in_sizes, int n_in,
                              void* d_out, int out_size, void* d_ws, size_t ws_size,
                              hipStream_t stream) {
    const int* value = (const int*)d_in[0];
    const int* depth = (const int*)d_in[1];
    const int* position = (const int*)d_in[2];
    const float* val_emb = (const float*)d_in[3];
    const float* dep_emb = (const float*)d_in[4];
    const float* pos_emb = (const float*)d_in[5];
    const float* w4 = (const float*)d_in[6];
    const float* b4 = (const float*)d_in[7];
    const float* w8 = (const float*)d_in[8];
    const float* b8 = (const float*)d_in[9];
    float* out = (float*)d_out;   // OUTPUT IS FLOAT32 (reference returns f32)

    short* wt4 = (short*)d_ws;            // 1024*256 bf16 = 512 KB
    short* wt8 = wt4 + 1024 * 256;        // 2048*256 bf16 = 1 MB

    transform_kernel<4><<<dim3(128), dim3(256), 0, stream>>>(w4, wt4);
    transform_kernel<8><<<dim3(256), dim3(256), 0, stream>>>(w8, wt8);
    embed_small_kernel<<<dim3(584), dim3(256), 0, stream>>>(value, depth, position,
                                                            val_emb, dep_emb, pos_emb, out);
    conv_kernel<4><<<dim3(128), dim3(256), 0, stream>>>(value, depth, position, val_emb,
                                                        dep_emb, pos_emb, wt4, b4, out);
    conv_kernel<8><<<dim3(512), dim3(256), 0, stream>>>(value, depth, position, val_emb,
                                                        dep_emb, pos_emb, wt8, b8, out);
}

// Round 9
// 132.217 us; speedup vs baseline: 2.1529x; 2.1529x over previous
//
#include <hip/hip_runtime.h>
#include <hip/hip_bf16.h>

// Problem constants
#define S_TOT 37448      // input tokens per sample
#define OUT_ROWS 5704    // output rows per sample
#define EDIM 256
#define BATCH 8

typedef __attribute__((ext_vector_type(8))) short short8;
typedef __attribute__((ext_vector_type(4))) float f32x4;

__device__ __forceinline__ short f2b(float f) {   // f32 -> bf16 RNE
    unsigned u = __builtin_bit_cast(unsigned, f);
    unsigned r = (u + 0x7fffu + ((u >> 16) & 1u)) >> 16;
    return (short)r;
}

__device__ __forceinline__ void embed8f(const float* ve, const float* de,
                                        const float* q0, const float* q1, const float* q2,
                                        float* s) {
#pragma unroll
    for (int h = 0; h < 2; ++h) {
        f32x4 a = *(const f32x4*)(ve + h * 4);
        f32x4 b = *(const f32x4*)(de + h * 4);
        f32x4 c = *(const f32x4*)(q0 + h * 4);
        f32x4 d = *(const f32x4*)(q1 + h * 4);
        f32x4 e = *(const f32x4*)(q2 + h * 4);
#pragma unroll
        for (int j = 0; j < 4; ++j)
            s[h * 4 + j] = a[j] + b[j] + c[j] + d[j] + e[j];
    }
}

// -------- weight pre-transform: w[o,i,k] (f32) -> bf16 MFMA B-fragment packed --------
// Wt2[((kb*16 + nf)*64 + l)*8 + j] = bf16(B[kb*32 + (l>>4)*8 + j][nf*16 + (l&15)])
// B[kappa][o] = w[o, i=kappa%256, kpos=kappa/256]
template <int S>
__global__ __launch_bounds__(256) void transform_kernel(const float* __restrict__ w,
                                                        short* __restrict__ dst) {
    int idx = blockIdx.x * 256 + threadIdx.x;
    int l  = idx & 63;
    int nf = (idx >> 6) & 15;
    int kb = idx >> 10;
    int o = nf * 16 + (l & 15);
    int kap0 = kb * 32 + ((l >> 4) << 3);
    short8 r;
#pragma unroll
    for (int j = 0; j < 8; ++j) {
        int kap = kap0 + j;
        int kpos = kap >> 8;
        int i = kap & 255;
        r[j] = f2b(w[(o * 256 + i) * S + kpos]);
    }
    *(short8*)(dst + idx * 8) = r;
}

// -------- precompute: P[k][R][o] = sum_i T[R][i] * w[o,i,k], via MFMA --------
// Stacked table rows R: [0,17)=val_emb, [17,81)=pos0, [81,145)=pos1,
// [145,209)=pos2, 209=dep(depth=LI+1), [210,256)=zero.
// Grid: S*4 blocks; blockIdx = k*4 + mt (mt = 64-row chunk).
template <int S>
__global__ __launch_bounds__(256) void precompute_kernel(
        const float* __restrict__ val_emb, const float* __restrict__ dep_emb,
        const float* __restrict__ pos_emb, const short* __restrict__ wt2,
        float* __restrict__ P) {
    constexpr int LI = (S == 4) ? 3 : 4;
    __shared__ __align__(16) short As[64 * 256];

    const int tid = threadIdx.x;
    const int lane = tid & 63;
    const int wid = tid >> 6;
    const int wave_m = wid >> 1;
    const int wave_n = wid & 1;
    const int k  = blockIdx.x >> 2;
    const int mt = blockIdx.x & 3;

    f32x4 acc[2][8];
#pragma unroll
    for (int i = 0; i < 2; ++i)
#pragma unroll
        for (int j = 0; j < 8; ++j) acc[i][j] = (f32x4){0.f, 0.f, 0.f, 0.f};

    const int tk = tid >> 5;
    const int f0 = (tid & 31) * 8;

#pragma unroll
    for (int m8 = 0; m8 < 8; ++m8) {
        int m = m8 * 8 + tk;
        int R = mt * 64 + m;
        const float* src;
        if (R < 17)        src = val_emb + (LI * 17 + R) * 256;
        else if (R < 81)   src = pos_emb + ((LI * 3 + 0) * 64 + R - 17) * 256;
        else if (R < 145)  src = pos_emb + ((LI * 3 + 1) * 64 + R - 81) * 256;
        else if (R < 209)  src = pos_emb + ((LI * 3 + 2) * 64 + R - 145) * 256;
        else if (R == 209) src = dep_emb + (LI * 33 + LI + 1) * 256;
        else               src = nullptr;
        short8 r;
        if (src) {
#pragma unroll
            for (int j = 0; j < 8; ++j) r[j] = f2b(src[f0 + j]);
        } else {
            r = (short8){0, 0, 0, 0, 0, 0, 0, 0};
        }
        int byte = (m * 512 + f0 * 2) ^ ((m & 7) << 4);
        *(short8*)((char*)As + byte) = r;
    }
    __syncthreads();

#pragma unroll
    for (int ks = 0; ks < 8; ++ks) {
        short8 af[2];
#pragma unroll
        for (int mf = 0; mf < 2; ++mf) {
            int m = wave_m * 32 + mf * 16 + (lane & 15);
            int byte = (m * 512 + ks * 64 + ((lane >> 4) << 4)) ^ ((m & 7) << 4);
            af[mf] = *(const short8*)((const char*)As + byte);
        }
        int kbg = k * 8 + ks;
#pragma unroll
        for (int nf = 0; nf < 8; ++nf) {
            int nfg = wave_n * 8 + nf;
            short8 bfr = *(const short8*)(wt2 + ((kbg * 16 + nfg) * 64 + lane) * 8);
            acc[0][nf] = __builtin_amdgcn_mfma_f32_16x16x32_bf16(af[0], bfr, acc[0][nf], 0, 0, 0);
            acc[1][nf] = __builtin_amdgcn_mfma_f32_16x16x32_bf16(af[1], bfr, acc[1][nf], 0, 0, 0);
        }
    }

#pragma unroll
    for (int mf = 0; mf < 2; ++mf) {
#pragma unroll
        for (int nf = 0; nf < 8; ++nf) {
            int n = wave_n * 128 + nf * 16 + (lane & 15);
            int r0 = mt * 64 + wave_m * 32 + mf * 16 + ((lane >> 4) << 2);
#pragma unroll
            for (int reg = 0; reg < 4; ++reg)
                P[(k * 256 + r0 + reg) * 256 + n] = acc[mf][nf][reg];
        }
    }
}

// bias2[o] = bias[o] + sum_k P[k][209][o]   (depth row folded into bias)
template <int S>
__global__ void fold_bias_kernel(const float* __restrict__ bias,
                                 const float* __restrict__ P,
                                 float* __restrict__ bias2) {
    int o = threadIdx.x;
    float s = bias[o];
#pragma unroll
    for (int k = 0; k < S; ++k) s += P[(k * 256 + 209) * 256 + o];
    bias2[o] = s;
}

// -------- main conv path: pure gather-sum of projected rows --------
// out[b, OFF_OUT+l, o] = bias2[o] + sum_k ( P[k][v][o] + P[k][17+p0][o]
//                                         + P[k][81+p1][o] + P[k][145+p2][o] )
template <int S>
__global__ __launch_bounds__(256) void gather_conv_kernel(
        const int* __restrict__ value, const int* __restrict__ position,
        const float* __restrict__ P, const float* __restrict__ bias2,
        float* __restrict__ out) {
    constexpr int L_OUT = (S == 4) ? 1024 : 4096;
    constexpr int OFF_IN = (S == 4) ? 584 : 4680;
    constexpr int OFF_OUT = (S == 4) ? 584 : 1608;

    int tid = threadIdx.x;
    int R = blockIdx.x * 8 + (tid >> 5);   // output row in [0, 8*L_OUT)
    int og = (tid & 31) * 8;
    int b = R / L_OUT;
    int l = R - b * L_OUT;

    f32x4 a0 = *(const f32x4*)(bias2 + og);
    f32x4 a1 = *(const f32x4*)(bias2 + og + 4);

    int base = b * S_TOT + OFF_IN + l * S;
#pragma unroll
    for (int k = 0; k < S; ++k) {
        int t = base + k;
        int v = value[t];
        const int* pp = position + t * 3;
        const float* Pk = P + (k << 16) + og;
        const float* r0 = Pk + (v << 8);
        const float* r1 = Pk + ((17 + pp[0]) << 8);
        const float* r2 = Pk + ((81 + pp[1]) << 8);
        const float* r3 = Pk + ((145 + pp[2]) << 8);
        a0 += *(const f32x4*)r0 + *(const f32x4*)r1 + *(const f32x4*)r2 + *(const f32x4*)r3;
        a1 += *(const f32x4*)(r0 + 4) + *(const f32x4*)(r1 + 4) +
              *(const f32x4*)(r2 + 4) + *(const f32x4*)(r3 + 4);
    }
    float* op = out + ((long)b * OUT_ROWS + OFF_OUT + l) * EDIM + og;
    *(f32x4*)op = a0;
    *(f32x4*)(op + 4) = a1;
}

// -------- layers 0..2: pure embedding, f32 out --------
__global__ __launch_bounds__(256) void embed_small_kernel(
        const int* __restrict__ value, const int* __restrict__ depth,
        const int* __restrict__ position, const float* __restrict__ val_emb,
        const float* __restrict__ dep_emb, const float* __restrict__ pos_emb,
        float* __restrict__ out) {
    int idx = blockIdx.x * 256 + threadIdx.x;
    int token = idx >> 5;
    int f0 = (idx & 31) * 8;
    int b = token / 584;
    int r = token - b * 584;
    int li = (r < 8) ? 0 : (r < 72 ? 1 : 2);
    int base = b * S_TOT + r;
    int v = value[base];
    int d = depth[base];
    const int* pp = position + base * 3;
    const float* ve = val_emb + ((li * 17 + v) << 8) + f0;
    const float* de = dep_emb + ((li * 33 + d) << 8) + f0;
    const float* q0 = pos_emb + (((li * 3 + 0) * 64 + pp[0]) << 8) + f0;
    const float* q1 = pos_emb + (((li * 3 + 1) * 64 + pp[1]) << 8) + f0;
    const float* q2 = pos_emb + (((li * 3 + 2) * 64 + pp[2]) << 8) + f0;
    float s[8];
    embed8f(ve, de, q0, q1, q2, s);
    float* op = out + ((long)b * OUT_ROWS + r) * EDIM + f0;
    *(f32x4*)op = (f32x4){s[0], s[1], s[2], s[3]};
    *(f32x4*)(op + 4) = (f32x4){s[4], s[5], s[6], s[7]};
}

// -------- FALLBACK (round-8 validated): fused embed + MFMA conv --------
template <int S>
__global__ __launch_bounds__(256) void conv_kernel(
        const int* __restrict__ value, const int* __restrict__ depth,
        const int* __restrict__ position, const float* __restrict__ val_emb,
        const float* __restrict__ dep_emb, const float* __restrict__ pos_emb,
        const short* __restrict__ wt2, const float* __restrict__ bias,
        float* __restrict__ out) {
    constexpr int LI = (S == 4) ? 3 : 4;
    constexpr int L_OUT = (S == 4) ? 1024 : 4096;
    constexpr int OFF_IN = (S == 4) ? 584 : 4680;
    constexpr int OFF_OUT = (S == 4) ? 584 : 1608;

    __shared__ __align__(16) short As[64 * 256];

    const int tid = threadIdx.x;
    const int lane = tid & 63;
    const int wid = tid >> 6;
    const int wave_m = wid >> 1;
    const int wave_n = wid & 1;
    const int mg0 = blockIdx.x * 64;
    const int b = mg0 / L_OUT;
    const int l0 = mg0 - b * L_OUT;

    f32x4 acc[2][8];
#pragma unroll
    for (int i = 0; i < 2; ++i)
#pragma unroll
        for (int j = 0; j < 8; ++j) acc[i][j] = (f32x4){0.f, 0.f, 0.f, 0.f};

    const int tk = tid >> 5;
    const int f0 = (tid & 31) * 8;

    for (int cp = 0; cp < S; ++cp) {
        __syncthreads();
#pragma unroll
        for (int m8 = 0; m8 < 8; ++m8) {
            int m = m8 * 8 + tk;
            int t = OFF_IN + (l0 + m) * S + cp;
            int base = b * S_TOT + t;
            int v = value[base];
            int d = depth[base];
            const int* pp = position + base * 3;
            const float* ve = val_emb + ((LI * 17 + v) << 8) + f0;
            const float* de = dep_emb + ((LI * 33 + d) << 8) + f0;
            const float* q0 = pos_emb + (((LI * 3 + 0) * 64 + pp[0]) << 8) + f0;
            const float* q1 = pos_emb + (((LI * 3 + 1) * 64 + pp[1]) << 8) + f0;
            const float* q2 = pos_emb + (((LI * 3 + 2) * 64 + pp[2]) << 8) + f0;
            float s[8];
            embed8f(ve, de, q0, q1, q2, s);
            short8 r;
#pragma unroll
            for (int j = 0; j < 8; ++j) r[j] = f2b(s[j]);
            int byte = (m * 512 + f0 * 2) ^ ((m & 7) << 4);
            *(short8*)((char*)As + byte) = r;
        }
        __syncthreads();
#pragma unroll
        for (int ks = 0; ks < 8; ++ks) {
            short8 af[2];
#pragma unroll
            for (int mf = 0; mf < 2; ++mf) {
                int m = wave_m * 32 + mf * 16 + (lane & 15);
                int byte = (m * 512 + ks * 64 + ((lane >> 4) << 4)) ^ ((m & 7) << 4);
                af[mf] = *(const short8*)((const char*)As + byte);
            }
            int kbg = cp * 8 + ks;
#pragma unroll
            for (int nf = 0; nf < 8; ++nf) {
                int nfg = wave_n * 8 + nf;
                short8 bfr = *(const short8*)(wt2 + ((kbg * 16 + nfg) * 64 + lane) * 8);
                acc[0][nf] = __builtin_amdgcn_mfma_f32_16x16x32_bf16(af[0], bfr, acc[0][nf], 0, 0, 0);
                acc[1][nf] = __builtin_amdgcn_mfma_f32_16x16x32_bf16(af[1], bfr, acc[1][nf], 0, 0, 0);
            }
        }
    }

#pragma unroll
    for (int mf = 0; mf < 2; ++mf) {
#pragma unroll
        for (int nf = 0; nf < 8; ++nf) {
            int n = wave_n * 128 + nf * 16 + (lane & 15);
            float bv = bias[n];
            int r0 = l0 + wave_m * 32 + mf * 16 + ((lane >> 4) << 2);
#pragma unroll
            for (int reg = 0; reg < 4; ++reg)
                out[((long)b * OUT_ROWS + OFF_OUT + r0 + reg) * EDIM + n] =
                    acc[mf][nf][reg] + bv;
        }
    }
}

extern "C" void kernel_launch(void* const* d_in, const int* in_sizes, int n_in,
                              void* d_out, int out_size, void* d_ws, size_t ws_size,
                              hipStream_t stream) {
    const int* value = (const int*)d_in[0];
    const int* depth = (const int*)d_in[1];
    const int* position = (const int*)d_in[2];
    const float* val_emb = (const float*)d_in[3];
    const float* dep_emb = (const float*)d_in[4];
    const float* pos_emb = (const float*)d_in[5];
    const float* w4 = (const float*)d_in[6];
    const float* b4 = (const float*)d_in[7];
    const float* w8 = (const float*)d_in[8];
    const float* b8 = (const float*)d_in[9];
    float* out = (float*)d_out;

    short* wt4 = (short*)d_ws;                 // 512 KB
    short* wt8 = wt4 + 262144;                 // 1 MB
    float* P4  = (float*)((char*)d_ws + 1572864);   // 1 MB  (4*256*256 f32)
    float* P8  = P4 + 262144;                  // 2 MB  (8*256*256 f32)
    float* bias2_4 = P8 + 524288;              // 1 KB
    float* bias2_8 = bias2_4 + 256;            // 1 KB
    const size_t need = 1572864 + 1048576 + 2097152 + 2048;

    transform_kernel<4><<<dim3(128), dim3(256), 0, stream>>>(w4, wt4);
    transform_kernel<8><<<dim3(256), dim3(256), 0, stream>>>(w8, wt8);
    embed_small_kernel<<<dim3(584), dim3(256), 0, stream>>>(value, depth, position,
                                                            val_emb, dep_emb, pos_emb, out);

    if (ws_size >= need) {
        precompute_kernel<4><<<dim3(16), dim3(256), 0, stream>>>(val_emb, dep_emb,
                                                                 pos_emb, wt4, P4);
        precompute_kernel<8><<<dim3(32), dim3(256), 0, stream>>>(val_emb, dep_emb,
                                                                 pos_emb, wt8, P8);
        fold_bias_kernel<4><<<dim3(1), dim3(256), 0, stream>>>(b4, P4, bias2_4);
        fold_bias_kernel<8><<<dim3(1), dim3(256), 0, stream>>>(b8, P8, bias2_8);
        gather_conv_kernel<4><<<dim3(1024), dim3(256), 0, stream>>>(value, position,
                                                                    P4, bias2_4, out);
        gather_conv_kernel<8><<<dim3(4096), dim3(256), 0, stream>>>(value, position,
                                                                    P8, bias2_8, out);
    } else {
        conv_kernel<4><<<dim3(128), dim3(256), 0, stream>>>(value, depth, position, val_emb,
                                                            dep_emb, pos_emb, wt4, b4, out);
        conv_kernel<8><<<dim3(512), dim3(256), 0, stream>>>(value, depth, position, val_emb,
                                                            dep_emb, pos_emb, wt8, b8, out);
    }
}

// Round 10
// 100.869 us; speedup vs baseline: 2.8219x; 1.3108x over previous
//
#include <hip/hip_runtime.h>
#include <hip/hip_bf16.h>

// Problem constants
#define S_TOT 37448      // input tokens per sample
#define OUT_ROWS 5704    // output rows per sample
#define EDIM 256
#define BATCH 8

typedef __attribute__((ext_vector_type(8))) short short8;
typedef __attribute__((ext_vector_type(4))) float f32x4;
typedef __attribute__((ext_vector_type(4))) unsigned int u32x4;

__device__ __forceinline__ short f2b(float f) {   // f32 -> bf16 RNE
    unsigned u = __builtin_bit_cast(unsigned, f);
    unsigned r = (u + 0x7fffu + ((u >> 16) & 1u)) >> 16;
    return (short)r;
}
__device__ __forceinline__ float b2f(short s) {
    unsigned u = ((unsigned)(unsigned short)s) << 16;
    return __builtin_bit_cast(float, u);
}

__device__ __forceinline__ void embed8f(const float* ve, const float* de,
                                        const float* q0, const float* q1, const float* q2,
                                        float* s) {
#pragma unroll
    for (int h = 0; h < 2; ++h) {
        f32x4 a = *(const f32x4*)(ve + h * 4);
        f32x4 b = *(const f32x4*)(de + h * 4);
        f32x4 c = *(const f32x4*)(q0 + h * 4);
        f32x4 d = *(const f32x4*)(q1 + h * 4);
        f32x4 e = *(const f32x4*)(q2 + h * 4);
#pragma unroll
        for (int j = 0; j < 4; ++j)
            s[h * 4 + j] = a[j] + b[j] + c[j] + d[j] + e[j];
    }
}

// unpack short8 (8 bf16) and add into a[0..7]
__device__ __forceinline__ void acc_bf8(float* a, short8 s) {
    u32x4 u = __builtin_bit_cast(u32x4, s);
#pragma unroll
    for (int j = 0; j < 4; ++j) {
        a[2 * j]     += __builtin_bit_cast(float, u[j] << 16);
        a[2 * j + 1] += __builtin_bit_cast(float, u[j] & 0xffff0000u);
    }
}

// -------- weight pre-transform: w[o,i,k] (f32) -> bf16 MFMA B-fragment packed --------
// Wt2[((kb*16 + nf)*64 + l)*8 + j] = bf16(B[kb*32 + (l>>4)*8 + j][nf*16 + (l&15)])
// B[kappa][o] = w[o, i=kappa%256, kpos=kappa/256]
template <int S>
__global__ __launch_bounds__(256) void transform_kernel(const float* __restrict__ w,
                                                        short* __restrict__ dst) {
    int idx = blockIdx.x * 256 + threadIdx.x;
    int l  = idx & 63;
    int nf = (idx >> 6) & 15;
    int kb = idx >> 10;
    int o = nf * 16 + (l & 15);
    int kap0 = kb * 32 + ((l >> 4) << 3);
    short8 r;
#pragma unroll
    for (int j = 0; j < 8; ++j) {
        int kap = kap0 + j;
        int kpos = kap >> 8;
        int i = kap & 255;
        r[j] = f2b(w[(o * 256 + i) * S + kpos]);
    }
    *(short8*)(dst + idx * 8) = r;
}

// -------- precompute: P[k][R][o] = sum_i T[R][i] * w[o,i,k]  (bf16 out) --------
// Stacked table rows R: [0,17)=val_emb, [17,81)=pos0, [81,145)=pos1,
// [145,209)=pos2, 209=dep(depth=LI+1), [210,256)=zero.
// Grid: S*4 blocks; blockIdx = k*4 + mt (mt = 64-row chunk).
template <int S>
__global__ __launch_bounds__(256) void precompute_kernel(
        const float* __restrict__ val_emb, const float* __restrict__ dep_emb,
        const float* __restrict__ pos_emb, const short* __restrict__ wt2,
        short* __restrict__ P) {
    constexpr int LI = (S == 4) ? 3 : 4;
    __shared__ __align__(16) short As[64 * 256];

    const int tid = threadIdx.x;
    const int lane = tid & 63;
    const int wid = tid >> 6;
    const int wave_m = wid >> 1;
    const int wave_n = wid & 1;
    const int k  = blockIdx.x >> 2;
    const int mt = blockIdx.x & 3;

    f32x4 acc[2][8];
#pragma unroll
    for (int i = 0; i < 2; ++i)
#pragma unroll
        for (int j = 0; j < 8; ++j) acc[i][j] = (f32x4){0.f, 0.f, 0.f, 0.f};

    const int tk = tid >> 5;
    const int f0 = (tid & 31) * 8;

#pragma unroll
    for (int m8 = 0; m8 < 8; ++m8) {
        int m = m8 * 8 + tk;
        int R = mt * 64 + m;
        const float* src;
        if (R < 17)        src = val_emb + (LI * 17 + R) * 256;
        else if (R < 81)   src = pos_emb + ((LI * 3 + 0) * 64 + R - 17) * 256;
        else if (R < 145)  src = pos_emb + ((LI * 3 + 1) * 64 + R - 81) * 256;
        else if (R < 209)  src = pos_emb + ((LI * 3 + 2) * 64 + R - 145) * 256;
        else if (R == 209) src = dep_emb + (LI * 33 + LI + 1) * 256;
        else               src = nullptr;
        short8 r;
        if (src) {
#pragma unroll
            for (int j = 0; j < 8; ++j) r[j] = f2b(src[f0 + j]);
        } else {
            r = (short8){0, 0, 0, 0, 0, 0, 0, 0};
        }
        int byte = (m * 512 + f0 * 2) ^ ((m & 7) << 4);
        *(short8*)((char*)As + byte) = r;
    }
    __syncthreads();

#pragma unroll
    for (int ks = 0; ks < 8; ++ks) {
        short8 af[2];
#pragma unroll
        for (int mf = 0; mf < 2; ++mf) {
            int m = wave_m * 32 + mf * 16 + (lane & 15);
            int byte = (m * 512 + ks * 64 + ((lane >> 4) << 4)) ^ ((m & 7) << 4);
            af[mf] = *(const short8*)((const char*)As + byte);
        }
        int kbg = k * 8 + ks;
#pragma unroll
        for (int nf = 0; nf < 8; ++nf) {
            int nfg = wave_n * 8 + nf;
            short8 bfr = *(const short8*)(wt2 + ((kbg * 16 + nfg) * 64 + lane) * 8);
            acc[0][nf] = __builtin_amdgcn_mfma_f32_16x16x32_bf16(af[0], bfr, acc[0][nf], 0, 0, 0);
            acc[1][nf] = __builtin_amdgcn_mfma_f32_16x16x32_bf16(af[1], bfr, acc[1][nf], 0, 0, 0);
        }
    }

#pragma unroll
    for (int mf = 0; mf < 2; ++mf) {
#pragma unroll
        for (int nf = 0; nf < 8; ++nf) {
            int n = wave_n * 128 + nf * 16 + (lane & 15);
            int r0 = mt * 64 + wave_m * 32 + mf * 16 + ((lane >> 4) << 2);
#pragma unroll
            for (int reg = 0; reg < 4; ++reg)
                P[(k * 256 + r0 + reg) * 256 + n] = f2b(acc[mf][nf][reg]);
        }
    }
}

// bias2[o] = bias[o] + sum_k P[k][209][o]   (depth row folded into bias)
template <int S>
__global__ void fold_bias_kernel(const float* __restrict__ bias,
                                 const short* __restrict__ P,
                                 float* __restrict__ bias2) {
    int o = threadIdx.x;
    float s = bias[o];
#pragma unroll
    for (int k = 0; k < S; ++k) s += b2f(P[(k * 256 + 209) * 256 + o]);
    bias2[o] = s;
}

// -------- main conv path: gather-sum of bf16 projected rows --------
// out[b, OFF_OUT+l, o] = bias2[o] + sum_k ( P[k][v][o] + P[k][17+p0][o]
//                                         + P[k][81+p1][o] + P[k][145+p2][o] )
// 8 rows/block; indices staged once in LDS by the first 8*S threads.
template <int S>
__global__ __launch_bounds__(256) void gather_conv_kernel(
        const int* __restrict__ value, const int* __restrict__ position,
        const short* __restrict__ P, const float* __restrict__ bias2,
        float* __restrict__ out) {
    constexpr int L_OUT = (S == 4) ? 1024 : 4096;
    constexpr int OFF_IN = (S == 4) ? 584 : 4680;
    constexpr int OFF_OUT = (S == 4) ? 584 : 1608;

    __shared__ int4 idx_lds[8][S];

    const int tid = threadIdx.x;
    const int R0 = blockIdx.x * 8;

    if (tid < 8 * S) {
        int r = tid / S, k = tid - (tid / S) * S;
        int R = R0 + r;
        int b = R / L_OUT, l = R - b * L_OUT;
        int t = b * S_TOT + OFF_IN + l * S + k;
        int v = value[t];
        const int* pp = position + t * 3;
        idx_lds[r][k] = make_int4(v << 8, (17 + pp[0]) << 8,
                                  (81 + pp[1]) << 8, (145 + pp[2]) << 8);
    }
    __syncthreads();

    const int r = tid >> 5;
    const int og = (tid & 31) * 8;
    const int R = R0 + r;
    const int b = R / L_OUT, l = R - b * L_OUT;

    float a[8];
    f32x4 b0 = *(const f32x4*)(bias2 + og);
    f32x4 b1 = *(const f32x4*)(bias2 + og + 4);
#pragma unroll
    for (int j = 0; j < 4; ++j) { a[j] = b0[j]; a[4 + j] = b1[j]; }

    const short* Pg = P + og;
#pragma unroll
    for (int k = 0; k < S; ++k) {
        int4 id = idx_lds[r][k];
        const short* Pk = Pg + (k << 16);
        short8 s0 = *(const short8*)(Pk + id.x);
        short8 s1 = *(const short8*)(Pk + id.y);
        short8 s2 = *(const short8*)(Pk + id.z);
        short8 s3 = *(const short8*)(Pk + id.w);
        acc_bf8(a, s0);
        acc_bf8(a, s1);
        acc_bf8(a, s2);
        acc_bf8(a, s3);
    }

    float* op = out + ((long)b * OUT_ROWS + OFF_OUT + l) * EDIM + og;
    *(f32x4*)op = (f32x4){a[0], a[1], a[2], a[3]};
    *(f32x4*)(op + 4) = (f32x4){a[4], a[5], a[6], a[7]};
}

// -------- layers 0..2: pure embedding, f32 out --------
__global__ __launch_bounds__(256) void embed_small_kernel(
        const int* __restrict__ value, const int* __restrict__ depth,
        const int* __restrict__ position, const float* __restrict__ val_emb,
        const float* __restrict__ dep_emb, const float* __restrict__ pos_emb,
        float* __restrict__ out) {
    int idx = blockIdx.x * 256 + threadIdx.x;
    int token = idx >> 5;
    int f0 = (idx & 31) * 8;
    int b = token / 584;
    int r = token - b * 584;
    int li = (r < 8) ? 0 : (r < 72 ? 1 : 2);
    int base = b * S_TOT + r;
    int v = value[base];
    int d = depth[base];
    const int* pp = position + base * 3;
    const float* ve = val_emb + ((li * 17 + v) << 8) + f0;
    const float* de = dep_emb + ((li * 33 + d) << 8) + f0;
    const float* q0 = pos_emb + (((li * 3 + 0) * 64 + pp[0]) << 8) + f0;
    const float* q1 = pos_emb + (((li * 3 + 1) * 64 + pp[1]) << 8) + f0;
    const float* q2 = pos_emb + (((li * 3 + 2) * 64 + pp[2]) << 8) + f0;
    float s[8];
    embed8f(ve, de, q0, q1, q2, s);
    float* op = out + ((long)b * OUT_ROWS + r) * EDIM + f0;
    *(f32x4*)op = (f32x4){s[0], s[1], s[2], s[3]};
    *(f32x4*)(op + 4) = (f32x4){s[4], s[5], s[6], s[7]};
}

// -------- FALLBACK (round-8 validated): fused embed + MFMA conv --------
template <int S>
__global__ __launch_bounds__(256) void conv_kernel(
        const int* __restrict__ value, const int* __restrict__ depth,
        const int* __restrict__ position, const float* __restrict__ val_emb,
        const float* __restrict__ dep_emb, const float* __restrict__ pos_emb,
        const short* __restrict__ wt2, const float* __restrict__ bias,
        float* __restrict__ out) {
    constexpr int LI = (S == 4) ? 3 : 4;
    constexpr int L_OUT = (S == 4) ? 1024 : 4096;
    constexpr int OFF_IN = (S == 4) ? 584 : 4680;
    constexpr int OFF_OUT = (S == 4) ? 584 : 1608;

    __shared__ __align__(16) short As[64 * 256];

    const int tid = threadIdx.x;
    const int lane = tid & 63;
    const int wid = tid >> 6;
    const int wave_m = wid >> 1;
    const int wave_n = wid & 1;
    const int mg0 = blockIdx.x * 64;
    const int b = mg0 / L_OUT;
    const int l0 = mg0 - b * L_OUT;

    f32x4 acc[2][8];
#pragma unroll
    for (int i = 0; i < 2; ++i)
#pragma unroll
        for (int j = 0; j < 8; ++j) acc[i][j] = (f32x4){0.f, 0.f, 0.f, 0.f};

    const int tk = tid >> 5;
    const int f0 = (tid & 31) * 8;

    for (int cp = 0; cp < S; ++cp) {
        __syncthreads();
#pragma unroll
        for (int m8 = 0; m8 < 8; ++m8) {
            int m = m8 * 8 + tk;
            int t = OFF_IN + (l0 + m) * S + cp;
            int base = b * S_TOT + t;
            int v = value[base];
            int d = depth[base];
            const int* pp = position + base * 3;
            const float* ve = val_emb + ((LI * 17 + v) << 8) + f0;
            const float* de = dep_emb + ((LI * 33 + d) << 8) + f0;
            const float* q0 = pos_emb + (((LI * 3 + 0) * 64 + pp[0]) << 8) + f0;
            const float* q1 = pos_emb + (((LI * 3 + 1) * 64 + pp[1]) << 8) + f0;
            const float* q2 = pos_emb + (((LI * 3 + 2) * 64 + pp[2]) << 8) + f0;
            float s[8];
            embed8f(ve, de, q0, q1, q2, s);
            short8 r;
#pragma unroll
            for (int j = 0; j < 8; ++j) r[j] = f2b(s[j]);
            int byte = (m * 512 + f0 * 2) ^ ((m & 7) << 4);
            *(short8*)((char*)As + byte) = r;
        }
        __syncthreads();
#pragma unroll
        for (int ks = 0; ks < 8; ++ks) {
            short8 af[2];
#pragma unroll
            for (int mf = 0; mf < 2; ++mf) {
                int m = wave_m * 32 + mf * 16 + (lane & 15);
                int byte = (m * 512 + ks * 64 + ((lane >> 4) << 4)) ^ ((m & 7) << 4);
                af[mf] = *(const short8*)((const char*)As + byte);
            }
            int kbg = cp * 8 + ks;
#pragma unroll
            for (int nf = 0; nf < 8; ++nf) {
                int nfg = wave_n * 8 + nf;
                short8 bfr = *(const short8*)(wt2 + ((kbg * 16 + nfg) * 64 + lane) * 8);
                acc[0][nf] = __builtin_amdgcn_mfma_f32_16x16x32_bf16(af[0], bfr, acc[0][nf], 0, 0, 0);
                acc[1][nf] = __builtin_amdgcn_mfma_f32_16x16x32_bf16(af[1], bfr, acc[1][nf], 0, 0, 0);
            }
        }
    }

#pragma unroll
    for (int mf = 0; mf < 2; ++mf) {
#pragma unroll
        for (int nf = 0; nf < 8; ++nf) {
            int n = wave_n * 128 + nf * 16 + (lane & 15);
            float bv = bias[n];
            int r0 = l0 + wave_m * 32 + mf * 16 + ((lane >> 4) << 2);
#pragma unroll
            for (int reg = 0; reg < 4; ++reg)
                out[((long)b * OUT_ROWS + OFF_OUT + r0 + reg) * EDIM + n] =
                    acc[mf][nf][reg] + bv;
        }
    }
}

extern "C" void kernel_launch(void* const* d_in, const int* in_sizes, int n_in,
                              void* d_out, int out_size, void* d_ws, size_t ws_size,
                              hipStream_t stream) {
    const int* value = (const int*)d_in[0];
    const int* depth = (const int*)d_in[1];
    const int* position = (const int*)d_in[2];
    const float* val_emb = (const float*)d_in[3];
    const float* dep_emb = (const float*)d_in[4];
    const float* pos_emb = (const float*)d_in[5];
    const float* w4 = (const float*)d_in[6];
    const float* b4 = (const float*)d_in[7];
    const float* w8 = (const float*)d_in[8];
    const float* b8 = (const float*)d_in[9];
    float* out = (float*)d_out;

    short* wt4 = (short*)d_ws;                          // 512 KB
    short* wt8 = wt4 + 262144;                          // 1 MB
    short* P4  = (short*)((char*)d_ws + 1572864);       // 512 KB (4*256*256 bf16)
    short* P8  = P4 + 262144;                           // 1 MB   (8*256*256 bf16)
    float* bias2_4 = (float*)((char*)d_ws + 3145728);   // 1 KB
    float* bias2_8 = bias2_4 + 256;                     // 1 KB
    const size_t need = 3145728 + 2048;

    transform_kernel<4><<<dim3(128), dim3(256), 0, stream>>>(w4, wt4);
    transform_kernel<8><<<dim3(256), dim3(256), 0, stream>>>(w8, wt8);
    embed_small_kernel<<<dim3(584), dim3(256), 0, stream>>>(value, depth, position,
                                                            val_emb, dep_emb, pos_emb, out);

    if (ws_size >= need) {
        precompute_kernel<4><<<dim3(16), dim3(256), 0, stream>>>(val_emb, dep_emb,
                                                                 pos_emb, wt4, P4);
        precompute_kernel<8><<<dim3(32), dim3(256), 0, stream>>>(val_emb, dep_emb,
                                                                 pos_emb, wt8, P8);
        fold_bias_kernel<4><<<dim3(1), dim3(256), 0, stream>>>(b4, P4, bias2_4);
        fold_bias_kernel<8><<<dim3(1), dim3(256), 0, stream>>>(b8, P8, bias2_8);
        gather_conv_kernel<4><<<dim3(1024), dim3(256), 0, stream>>>(value, position,
                                                                    P4, bias2_4, out);
        gather_conv_kernel<8><<<dim3(4096), dim3(256), 0, stream>>>(value, position,
                                                                    P8, bias2_8, out);
    } else {
        conv_kernel<4><<<dim3(128), dim3(256), 0, stream>>>(value, depth, position, val_emb,
                                                            dep_emb, pos_emb, wt4, b4, out);
        conv_kernel<8><<<dim3(512), dim3(256), 0, stream>>>(value, depth, position, val_emb,
                                                            dep_emb, pos_emb, wt8, b8, out);
    }
}

// Round 11
// 62.421 us; speedup vs baseline: 4.5601x; 1.6160x over previous
//
#include <hip/hip_runtime.h>
#include <hip/hip_bf16.h>

// Problem constants
#define S_TOT 37448      // input tokens per sample
#define OUT_ROWS 5704    // output rows per sample
#define EDIM 256
#define BATCH 8

typedef __attribute__((ext_vector_type(8))) short short8;
typedef __attribute__((ext_vector_type(4))) float f32x4;
typedef __attribute__((ext_vector_type(4))) unsigned int u32x4;

__device__ __forceinline__ short f2b(float f) {   // f32 -> bf16 RNE
    unsigned u = __builtin_bit_cast(unsigned, f);
    unsigned r = (u + 0x7fffu + ((u >> 16) & 1u)) >> 16;
    return (short)r;
}
__device__ __forceinline__ float b2f(short s) {
    unsigned u = ((unsigned)(unsigned short)s) << 16;
    return __builtin_bit_cast(float, u);
}

__device__ __forceinline__ void embed8f(const float* ve, const float* de,
                                        const float* q0, const float* q1, const float* q2,
                                        float* s) {
#pragma unroll
    for (int h = 0; h < 2; ++h) {
        f32x4 a = *(const f32x4*)(ve + h * 4);
        f32x4 b = *(const f32x4*)(de + h * 4);
        f32x4 c = *(const f32x4*)(q0 + h * 4);
        f32x4 d = *(const f32x4*)(q1 + h * 4);
        f32x4 e = *(const f32x4*)(q2 + h * 4);
#pragma unroll
        for (int j = 0; j < 4; ++j)
            s[h * 4 + j] = a[j] + b[j] + c[j] + d[j] + e[j];
    }
}

// unpack short8 (8 bf16) and add into a[0..7]
__device__ __forceinline__ void acc_bf8(float* a, short8 s) {
    u32x4 u = __builtin_bit_cast(u32x4, s);
#pragma unroll
    for (int j = 0; j < 4; ++j) {
        a[2 * j]     += __builtin_bit_cast(float, u[j] << 16);
        a[2 * j + 1] += __builtin_bit_cast(float, u[j] & 0xffff0000u);
    }
}

// -------- weight pre-transform: w[o,i,k] (f32) -> bf16 MFMA B-fragment packed --------
// Wt2[((kb*16 + nf)*64 + l)*8 + j] = bf16(B[kb*32 + (l>>4)*8 + j][nf*16 + (l&15)])
// B[kappa][o] = w[o, i=kappa%256, kpos=kappa/256]
template <int S>
__device__ __forceinline__ void transform_body(const float* __restrict__ w,
                                               short* __restrict__ dst, int bid, int tid) {
    int idx = bid * 256 + tid;
    int l  = idx & 63;
    int nf = (idx >> 6) & 15;
    int kb = idx >> 10;
    int o = nf * 16 + (l & 15);
    int kap0 = kb * 32 + ((l >> 4) << 3);
    short8 r;
#pragma unroll
    for (int j = 0; j < 8; ++j) {
        int kap = kap0 + j;
        int kpos = kap >> 8;
        int i = kap & 255;
        r[j] = f2b(w[(o * 256 + i) * S + kpos]);
    }
    *(short8*)(dst + idx * 8) = r;
}

__global__ __launch_bounds__(256) void transform_both(
        const float* __restrict__ w4, const float* __restrict__ w8,
        short* __restrict__ wt4, short* __restrict__ wt8) {
    int bid = blockIdx.x, tid = threadIdx.x;
    if (bid < 128) transform_body<4>(w4, wt4, bid, tid);
    else           transform_body<8>(w8, wt8, bid - 128, tid);
}

// -------- precompute: P[k][R][o] = sum_i T[R][i] * w[o,i,k]  (bf16 out) --------
// Stacked table rows R: [0,17)=val_emb+DEP-ROW (depth folded), [17,81)=pos0,
// [81,145)=pos1, [145,209)=pos2, [209,256)=zero.
// bid = k*4 + mt (mt = 64-row chunk).
template <int S>
__device__ __forceinline__ void precompute_body(
        const float* __restrict__ val_emb, const float* __restrict__ dep_emb,
        const float* __restrict__ pos_emb, const short* __restrict__ wt2,
        short* __restrict__ P, int bid, int tid, short* As) {
    constexpr int LI = (S == 4) ? 3 : 4;
    const int lane = tid & 63;
    const int wid = tid >> 6;
    const int wave_m = wid >> 1;
    const int wave_n = wid & 1;
    const int k  = bid >> 2;
    const int mt = bid & 3;

    f32x4 acc[2][8];
#pragma unroll
    for (int i = 0; i < 2; ++i)
#pragma unroll
        for (int j = 0; j < 8; ++j) acc[i][j] = (f32x4){0.f, 0.f, 0.f, 0.f};

    const int tk = tid >> 5;
    const int f0 = (tid & 31) * 8;
    const float* dep = dep_emb + (LI * 33 + LI + 1) * 256;   // depth row for this layer

#pragma unroll
    for (int m8 = 0; m8 < 8; ++m8) {
        int m = m8 * 8 + tk;
        int R = mt * 64 + m;
        short8 r;
        if (R < 17) {
            const float* src = val_emb + (LI * 17 + R) * 256;
#pragma unroll
            for (int j = 0; j < 8; ++j) r[j] = f2b(src[f0 + j] + dep[f0 + j]);
        } else if (R < 209) {
            int ax = (R < 81) ? 0 : (R < 145 ? 1 : 2);
            int rr = R - (ax == 0 ? 17 : (ax == 1 ? 81 : 145));
            const float* src = pos_emb + ((LI * 3 + ax) * 64 + rr) * 256;
#pragma unroll
            for (int j = 0; j < 8; ++j) r[j] = f2b(src[f0 + j]);
        } else {
            r = (short8){0, 0, 0, 0, 0, 0, 0, 0};
        }
        int byte = (m * 512 + f0 * 2) ^ ((m & 7) << 4);
        *(short8*)((char*)As + byte) = r;
    }
    __syncthreads();

#pragma unroll
    for (int ks = 0; ks < 8; ++ks) {
        short8 af[2];
#pragma unroll
        for (int mf = 0; mf < 2; ++mf) {
            int m = wave_m * 32 + mf * 16 + (lane & 15);
            int byte = (m * 512 + ks * 64 + ((lane >> 4) << 4)) ^ ((m & 7) << 4);
            af[mf] = *(const short8*)((const char*)As + byte);
        }
        int kbg = k * 8 + ks;
#pragma unroll
        for (int nf = 0; nf < 8; ++nf) {
            int nfg = wave_n * 8 + nf;
            short8 bfr = *(const short8*)(wt2 + ((kbg * 16 + nfg) * 64 + lane) * 8);
            acc[0][nf] = __builtin_amdgcn_mfma_f32_16x16x32_bf16(af[0], bfr, acc[0][nf], 0, 0, 0);
            acc[1][nf] = __builtin_amdgcn_mfma_f32_16x16x32_bf16(af[1], bfr, acc[1][nf], 0, 0, 0);
        }
    }

#pragma unroll
    for (int mf = 0; mf < 2; ++mf) {
#pragma unroll
        for (int nf = 0; nf < 8; ++nf) {
            int n = wave_n * 128 + nf * 16 + (lane & 15);
            int r0 = mt * 64 + wave_m * 32 + mf * 16 + ((lane >> 4) << 2);
#pragma unroll
            for (int reg = 0; reg < 4; ++reg)
                P[(k * 256 + r0 + reg) * 256 + n] = f2b(acc[mf][nf][reg]);
        }
    }
}

__global__ __launch_bounds__(256) void precompute_both(
        const float* __restrict__ val_emb, const float* __restrict__ dep_emb,
        const float* __restrict__ pos_emb, const short* __restrict__ wt4,
        const short* __restrict__ wt8, short* __restrict__ P4, short* __restrict__ P8) {
    __shared__ __align__(16) short As[64 * 256];
    if (blockIdx.x < 16)
        precompute_body<4>(val_emb, dep_emb, pos_emb, wt4, P4, blockIdx.x, threadIdx.x, As);
    else
        precompute_body<8>(val_emb, dep_emb, pos_emb, wt8, P8, blockIdx.x - 16, threadIdx.x, As);
}

// -------- gather-sum of bf16 projected rows (depth pre-folded, plain bias) --------
template <int S>
__device__ __forceinline__ void gather_body(
        const int* __restrict__ value, const int* __restrict__ position,
        const short* __restrict__ P, const float* __restrict__ bias,
        float* __restrict__ out, int bid, int tid, int4* idx_lds) {
    constexpr int L_OUT = (S == 4) ? 1024 : 4096;
    constexpr int OFF_IN = (S == 4) ? 584 : 4680;
    constexpr int OFF_OUT = (S == 4) ? 584 : 1608;

    const int R0 = bid * 8;
    if (tid < 8 * S) {
        int r = tid / S, k = tid - r * S;
        int R = R0 + r;
        int b = R / L_OUT, l = R - b * L_OUT;
        int t = b * S_TOT + OFF_IN + l * S + k;
        int v = value[t];
        const int* pp = position + t * 3;
        idx_lds[r * S + k] = make_int4(v << 8, (17 + pp[0]) << 8,
                                       (81 + pp[1]) << 8, (145 + pp[2]) << 8);
    }
    __syncthreads();

    const int r = tid >> 5;
    const int og = (tid & 31) * 8;
    const int R = R0 + r;
    const int b = R / L_OUT, l = R - b * L_OUT;

    float a[8];
    f32x4 b0 = *(const f32x4*)(bias + og);
    f32x4 b1 = *(const f32x4*)(bias + og + 4);
#pragma unroll
    for (int j = 0; j < 4; ++j) { a[j] = b0[j]; a[4 + j] = b1[j]; }

    const short* Pg = P + og;
#pragma unroll
    for (int k = 0; k < S; ++k) {
        int4 id = idx_lds[r * S + k];
        const short* Pk = Pg + (k << 16);
        short8 s0 = *(const short8*)(Pk + id.x);
        short8 s1 = *(const short8*)(Pk + id.y);
        short8 s2 = *(const short8*)(Pk + id.z);
        short8 s3 = *(const short8*)(Pk + id.w);
        acc_bf8(a, s0);
        acc_bf8(a, s1);
        acc_bf8(a, s2);
        acc_bf8(a, s3);
    }

    float* op = out + ((long)b * OUT_ROWS + OFF_OUT + l) * EDIM + og;
    *(f32x4*)op = (f32x4){a[0], a[1], a[2], a[3]};
    *(f32x4*)(op + 4) = (f32x4){a[4], a[5], a[6], a[7]};
}

// -------- layers 0..2: pure embedding, f32 out --------
__device__ __forceinline__ void embed_small_body(
        const int* __restrict__ value, const int* __restrict__ depth,
        const int* __restrict__ position, const float* __restrict__ val_emb,
        const float* __restrict__ dep_emb, const float* __restrict__ pos_emb,
        float* __restrict__ out, int bid, int tid) {
    int idx = bid * 256 + tid;
    int token = idx >> 5;
    int f0 = (idx & 31) * 8;
    int b = token / 584;
    int r = token - b * 584;
    int li = (r < 8) ? 0 : (r < 72 ? 1 : 2);
    int base = b * S_TOT + r;
    int v = value[base];
    int d = depth[base];
    const int* pp = position + base * 3;
    const float* ve = val_emb + ((li * 17 + v) << 8) + f0;
    const float* de = dep_emb + ((li * 33 + d) << 8) + f0;
    const float* q0 = pos_emb + (((li * 3 + 0) * 64 + pp[0]) << 8) + f0;
    const float* q1 = pos_emb + (((li * 3 + 1) * 64 + pp[1]) << 8) + f0;
    const float* q2 = pos_emb + (((li * 3 + 2) * 64 + pp[2]) << 8) + f0;
    float s[8];
    embed8f(ve, de, q0, q1, q2, s);
    float* op = out + ((long)b * OUT_ROWS + r) * EDIM + f0;
    *(f32x4*)op = (f32x4){s[0], s[1], s[2], s[3]};
    *(f32x4*)(op + 4) = (f32x4){s[4], s[5], s[6], s[7]};
}

// -------- mega kernel: gather8 | gather4 | small-embed, one launch --------
__global__ __launch_bounds__(256) void gather_mega(
        const int* __restrict__ value, const int* __restrict__ depth,
        const int* __restrict__ position, const float* __restrict__ val_emb,
        const float* __restrict__ dep_emb, const float* __restrict__ pos_emb,
        const short* __restrict__ P4, const short* __restrict__ P8,
        const float* __restrict__ b4, const float* __restrict__ b8,
        float* __restrict__ out) {
    __shared__ int4 idx_lds[64];
    int bid = blockIdx.x, tid = threadIdx.x;
    if (bid < 4096)
        gather_body<8>(value, position, P8, b8, out, bid, tid, idx_lds);
    else if (bid < 5120)
        gather_body<4>(value, position, P4, b4, out, bid - 4096, tid, idx_lds);
    else
        embed_small_body(value, depth, position, val_emb, dep_emb, pos_emb, out, bid - 5120, tid);
}

// -------- FALLBACK (round-8 validated): fused embed + MFMA conv --------
template <int S>
__global__ __launch_bounds__(256) void conv_kernel(
        const int* __restrict__ value, const int* __restrict__ depth,
        const int* __restrict__ position, const float* __restrict__ val_emb,
        const float* __restrict__ dep_emb, const float* __restrict__ pos_emb,
        const short* __restrict__ wt2, const float* __restrict__ bias,
        float* __restrict__ out) {
    constexpr int LI = (S == 4) ? 3 : 4;
    constexpr int L_OUT = (S == 4) ? 1024 : 4096;
    constexpr int OFF_IN = (S == 4) ? 584 : 4680;
    constexpr int OFF_OUT = (S == 4) ? 584 : 1608;

    __shared__ __align__(16) short As[64 * 256];

    const int tid = threadIdx.x;
    const int lane = tid & 63;
    const int wid = tid >> 6;
    const int wave_m = wid >> 1;
    const int wave_n = wid & 1;
    const int mg0 = blockIdx.x * 64;
    const int b = mg0 / L_OUT;
    const int l0 = mg0 - b * L_OUT;

    f32x4 acc[2][8];
#pragma unroll
    for (int i = 0; i < 2; ++i)
#pragma unroll
        for (int j = 0; j < 8; ++j) acc[i][j] = (f32x4){0.f, 0.f, 0.f, 0.f};

    const int tk = tid >> 5;
    const int f0 = (tid & 31) * 8;

    for (int cp = 0; cp < S; ++cp) {
        __syncthreads();
#pragma unroll
        for (int m8 = 0; m8 < 8; ++m8) {
            int m = m8 * 8 + tk;
            int t = OFF_IN + (l0 + m) * S + cp;
            int base = b * S_TOT + t;
            int v = value[base];
            int d = depth[base];
            const int* pp = position + base * 3;
            const float* ve = val_emb + ((LI * 17 + v) << 8) + f0;
            const float* de = dep_emb + ((LI * 33 + d) << 8) + f0;
            const float* q0 = pos_emb + (((LI * 3 + 0) * 64 + pp[0]) << 8) + f0;
            const float* q1 = pos_emb + (((LI * 3 + 1) * 64 + pp[1]) << 8) + f0;
            const float* q2 = pos_emb + (((LI * 3 + 2) * 64 + pp[2]) << 8) + f0;
            float s[8];
            embed8f(ve, de, q0, q1, q2, s);
            short8 r;
#pragma unroll
            for (int j = 0; j < 8; ++j) r[j] = f2b(s[j]);
            int byte = (m * 512 + f0 * 2) ^ ((m & 7) << 4);
            *(short8*)((char*)As + byte) = r;
        }
        __syncthreads();
#pragma unroll
        for (int ks = 0; ks < 8; ++ks) {
            short8 af[2];
#pragma unroll
            for (int mf = 0; mf < 2; ++mf) {
                int m = wave_m * 32 + mf * 16 + (lane & 15);
                int byte = (m * 512 + ks * 64 + ((lane >> 4) << 4)) ^ ((m & 7) << 4);
                af[mf] = *(const short8*)((const char*)As + byte);
            }
            int kbg = cp * 8 + ks;
#pragma unroll
            for (int nf = 0; nf < 8; ++nf) {
                int nfg = wave_n * 8 + nf;
                short8 bfr = *(const short8*)(wt2 + ((kbg * 16 + nfg) * 64 + lane) * 8);
                acc[0][nf] = __builtin_amdgcn_mfma_f32_16x16x32_bf16(af[0], bfr, acc[0][nf], 0, 0, 0);
                acc[1][nf] = __builtin_amdgcn_mfma_f32_16x16x32_bf16(af[1], bfr, acc[1][nf], 0, 0, 0);
            }
        }
    }

#pragma unroll
    for (int mf = 0; mf < 2; ++mf) {
#pragma unroll
        for (int nf = 0; nf < 8; ++nf) {
            int n = wave_n * 128 + nf * 16 + (lane & 15);
            float bv = bias[n];
            int r0 = l0 + wave_m * 32 + mf * 16 + ((lane >> 4) << 2);
#pragma unroll
            for (int reg = 0; reg < 4; ++reg)
                out[((long)b * OUT_ROWS + OFF_OUT + r0 + reg) * EDIM + n] =
                    acc[mf][nf][reg] + bv;
        }
    }
}

__global__ __launch_bounds__(256) void embed_small_kernel(
        const int* __restrict__ value, const int* __restrict__ depth,
        const int* __restrict__ position, const float* __restrict__ val_emb,
        const float* __restrict__ dep_emb, const float* __restrict__ pos_emb,
        float* __restrict__ out) {
    embed_small_body(value, depth, position, val_emb, dep_emb, pos_emb, out,
                     blockIdx.x, threadIdx.x);
}

extern "C" void kernel_launch(void* const* d_in, const int* in_sizes, int n_in,
                              void* d_out, int out_size, void* d_ws, size_t ws_size,
                              hipStream_t stream) {
    const int* value = (const int*)d_in[0];
    const int* depth = (const int*)d_in[1];
    const int* position = (const int*)d_in[2];
    const float* val_emb = (const float*)d_in[3];
    const float* dep_emb = (const float*)d_in[4];
    const float* pos_emb = (const float*)d_in[5];
    const float* w4 = (const float*)d_in[6];
    const float* b4 = (const float*)d_in[7];
    const float* w8 = (const float*)d_in[8];
    const float* b8 = (const float*)d_in[9];
    float* out = (float*)d_out;

    short* wt4 = (short*)d_ws;                          // 512 KB
    short* wt8 = wt4 + 262144;                          // 1 MB
    short* P4  = (short*)((char*)d_ws + 1572864);       // 512 KB (4*256*256 bf16)
    short* P8  = P4 + 262144;                           // 1 MB   (8*256*256 bf16)
    const size_t need = 3145728;

    transform_both<<<dim3(384), dim3(256), 0, stream>>>(w4, w8, wt4, wt8);

    if (ws_size >= need) {
        precompute_both<<<dim3(48), dim3(256), 0, stream>>>(val_emb, dep_emb, pos_emb,
                                                            wt4, wt8, P4, P8);
        gather_mega<<<dim3(5704), dim3(256), 0, stream>>>(value, depth, position,
                                                          val_emb, dep_emb, pos_emb,
                                                          P4, P8, b4, b8, out);
    } else {
        embed_small_kernel<<<dim3(584), dim3(256), 0, stream>>>(value, depth, position,
                                                                val_emb, dep_emb, pos_emb, out);
        conv_kernel<4><<<dim3(128), dim3(256), 0, stream>>>(value, depth, position, val_emb,
                                                            dep_emb, pos_emb, wt4, b4, out);
        conv_kernel<8><<<dim3(512), dim3(256), 0, stream>>>(value, depth, position, val_emb,
                                                            dep_emb, pos_emb, wt8, b8, out);
    }
}